// Round 1
// baseline (799.065 us; speedup 1.0000x reference)
//
#include <hip/hip_runtime.h>
#include <math.h>

#define BB 4
#define SS 4096
#define DD 64

#define NCHUNK 8
#define QCH (SS/NCHUNK)   // 512
#define QB 32             // q rows staged per LDS tile in K1

#define QT 32             // q rows per block in K3
#define NCH2 32
#define QC2 (SS/NCH2)     // 128

// ---------------- K1: partial column stats (max, sumexp) of scores over a q-chunk
// grid (SS/256, NCHUNK, BB), block 256. Thread owns one k-column.
__global__ __launch_bounds__(256) void k1_colstats(
    const float* __restrict__ q, const float* __restrict__ k,
    float* __restrict__ pm, float* __restrict__ pz)
{
    const int col = blockIdx.x * 256 + threadIdx.x;
    const int ch  = blockIdx.y;
    const int b   = blockIdx.z;

    float kr[DD];
    const float* kp = k + ((size_t)b * SS + col) * DD;
#pragma unroll
    for (int d = 0; d < DD; ++d) kr[d] = kp[d];

    __shared__ float qs[QB][DD];

    float m = -1e30f, z = 0.f;
    const float inv = 1.0f / 64.0f;

    for (int q0 = ch * QCH; q0 < (ch + 1) * QCH; q0 += QB) {
        __syncthreads();
        const float4* src = (const float4*)(q + ((size_t)b * SS + q0) * DD);
        float4* dst = (float4*)&qs[0][0];
        for (int i = threadIdx.x; i < QB * DD / 4; i += 256) dst[i] = src[i];
        __syncthreads();

#pragma unroll 1
        for (int j = 0; j < QB; ++j) {
            float s = 0.f;
#pragma unroll
            for (int d = 0; d < DD; ++d) s += kr[d] * qs[j][d];
            s *= inv;
            float mn = fmaxf(m, s);
            z = z * __expf(m - mn) + __expf(s - mn);
            m = mn;
        }
    }
    pm[((size_t)ch * BB + b) * SS + col] = m;
    pz[((size_t)ch * BB + b) * SS + col] = z;
}

// ---------------- K2: combine chunk partials -> colmax, 1/Z
__global__ __launch_bounds__(256) void k2_combine(
    const float* __restrict__ pm, const float* __restrict__ pz,
    float* __restrict__ cm, float* __restrict__ cz)
{
    const size_t idx = (size_t)blockIdx.x * 256 + threadIdx.x;  // over BB*SS
    float m = -1e30f;
#pragma unroll
    for (int c = 0; c < NCHUNK; ++c) m = fmaxf(m, pm[(size_t)c * BB * SS + idx]);
    float z = 0.f;
#pragma unroll
    for (int c = 0; c < NCHUNK; ++c)
        z += pz[(size_t)c * BB * SS + idx] * __expf(pm[(size_t)c * BB * SS + idx] - m);
    cm[idx] = m;
    cz[idx] = 1.0f / z;
}

// ---------------- K3: recompute scores tile-wise, probs, PV -> attn
// grid (SS/QT, 1, BB), block 256 (4 waves). Each wave -> 8 q rows in phase B.
__global__ __launch_bounds__(256) void k3_attn(
    const float* __restrict__ q, const float* __restrict__ k, const float* __restrict__ v,
    const float* __restrict__ cm, const float* __restrict__ cz,
    float* __restrict__ attn)
{
    const int b  = blockIdx.z;
    const int q0 = blockIdx.x * QT;
    const int t  = threadIdx.x;
    const int lane = t & 63;
    const int w    = t >> 6;

    __shared__ float qs[QT][DD];         // 8 KB
    __shared__ float ks[64][DD + 4];     // 17 KB (padded rows, 16B-aligned)
    __shared__ float vs[64][DD];         // 16 KB
    __shared__ float wsm[QT][64];        // 8 KB
    __shared__ float msh[64], zsh[64];

    {
        const float4* src = (const float4*)(q + ((size_t)b * SS + q0) * DD);
        float4* dst = (float4*)&qs[0][0];
        for (int i = t; i < QT * DD / 4; i += 256) dst[i] = src[i];
    }

    float acc[8];
#pragma unroll
    for (int i = 0; i < 8; ++i) acc[i] = 0.f;
    const float inv = 1.0f / 64.0f;

    for (int k0 = 0; k0 < SS; k0 += 64) {
        __syncthreads();
        {
            const float4* srck = (const float4*)(k + ((size_t)b * SS + k0) * DD);
            const float4* srcv = (const float4*)(v + ((size_t)b * SS + k0) * DD);
            for (int i = t; i < 64 * DD / 4; i += 256) {
                int r = i / (DD / 4), c = i % (DD / 4);
                ((float4*)&ks[r][0])[c] = srck[i];
            }
            for (int i = t; i < 64 * DD / 4; i += 256) ((float4*)&vs[0][0])[i] = srcv[i];
            if (t < 64) {
                msh[t] = cm[(size_t)b * SS + k0 + t];
                zsh[t] = cz[(size_t)b * SS + k0 + t];
            }
        }
        __syncthreads();

        // phase A: s[qq][lane] for qq = w + 4*i
        {
            float sacc[8];
#pragma unroll
            for (int i = 0; i < 8; ++i) sacc[i] = 0.f;
            for (int d4 = 0; d4 < DD / 4; ++d4) {
                float4 kk = ((const float4*)&ks[lane][0])[d4];
#pragma unroll
                for (int i = 0; i < 8; ++i) {
                    const int qq = w + 4 * i;
                    float4 qv = ((const float4*)&qs[qq][0])[d4];
                    sacc[i] += qv.x * kk.x + qv.y * kk.y + qv.z * kk.z + qv.w * kk.w;
                }
            }
            const float mk = msh[lane], zk = zsh[lane];
#pragma unroll
            for (int i = 0; i < 8; ++i) {
                const int qq = w + 4 * i;
                wsm[qq][lane] = __expf(sacc[i] * inv - mk) * zk;
            }
        }
        __syncthreads();

        // phase B: acc[i] += sum_k wsm[w*8+i][kk] * vs[kk][lane]
#pragma unroll 1
        for (int kk = 0; kk < 64; ++kk) {
            float vv = vs[kk][lane];
#pragma unroll
            for (int i = 0; i < 8; ++i) acc[i] += wsm[w * 8 + i][kk] * vv;
        }
    }

#pragma unroll
    for (int i = 0; i < 8; ++i)
        attn[((size_t)b * SS + q0 + w * 8 + i) * DD + lane] = acc[i];
}

// ---------------- K4: partial stats over q of attn, per (b,d)
__global__ __launch_bounds__(64) void k4_stats(
    const float* __restrict__ attn, float* __restrict__ pm2, float* __restrict__ pz2)
{
    const int b = blockIdx.x, ch = blockIdx.y;
    const int d = threadIdx.x;
    float m = -1e30f, z = 0.f;
    for (int qq = ch * QC2; qq < (ch + 1) * QC2; ++qq) {
        float a = attn[((size_t)b * SS + qq) * DD + d];
        float mn = fmaxf(m, a);
        z = z * __expf(m - mn) + __expf(a - mn);
        m = mn;
    }
    pm2[(ch * BB + b) * DD + d] = m;
    pz2[(ch * BB + b) * DD + d] = z;
}

// ---------------- K5: combine -> m2, 1/Z2 (BB*DD = 256 columns)
__global__ __launch_bounds__(256) void k5_combine2(
    const float* __restrict__ pm2, const float* __restrict__ pz2,
    float* __restrict__ m2, float* __restrict__ iz2)
{
    const int idx = threadIdx.x;  // b*DD + d
    float m = -1e30f;
#pragma unroll
    for (int c = 0; c < NCH2; ++c) m = fmaxf(m, pm2[c * BB * DD + idx]);
    float z = 0.f;
#pragma unroll
    for (int c = 0; c < NCH2; ++c) z += pz2[c * BB * DD + idx] * __expf(pm2[c * BB * DD + idx] - m);
    m2[idx] = m;
    iz2[idx] = 1.0f / z;
}

// ---------------- K6: attn_w = exp(attn - m2) * iz2
__global__ __launch_bounds__(256) void k6_write(
    const float* __restrict__ attn, const float* __restrict__ m2,
    const float* __restrict__ iz2, float* __restrict__ out1)
{
    const size_t i = (size_t)blockIdx.x * 256 + threadIdx.x;  // over BB*SS*DD
    const int b = (int)(i / ((size_t)SS * DD));
    const int d = (int)(i % DD);
    const int cidx = b * DD + d;
    out1[i] = __expf(attn[i] - m2[cidx]) * iz2[cidx];
}

extern "C" void kernel_launch(void* const* d_in, const int* in_sizes, int n_in,
                              void* d_out, int out_size, void* d_ws, size_t ws_size,
                              hipStream_t stream) {
    const float* q = (const float*)d_in[0];
    const float* k = (const float*)d_in[1];
    const float* v = (const float*)d_in[2];
    float* out0 = (float*)d_out;                       // attn
    float* out1 = out0 + (size_t)BB * SS * DD;         // attn_w

    float* ws  = (float*)d_ws;
    float* pm  = ws; ws += (size_t)NCHUNK * BB * SS;
    float* pz  = ws; ws += (size_t)NCHUNK * BB * SS;
    float* cm  = ws; ws += (size_t)BB * SS;
    float* cz  = ws; ws += (size_t)BB * SS;
    float* pm2 = ws; ws += (size_t)NCH2 * BB * DD;
    float* pz2 = ws; ws += (size_t)NCH2 * BB * DD;
    float* m2  = ws; ws += (size_t)BB * DD;
    float* iz2 = ws; ws += (size_t)BB * DD;

    hipLaunchKernelGGL(k1_colstats, dim3(SS / 256, NCHUNK, BB), dim3(256), 0, stream, q, k, pm, pz);
    hipLaunchKernelGGL(k2_combine, dim3(BB * SS / 256), dim3(256), 0, stream, pm, pz, cm, cz);
    hipLaunchKernelGGL(k3_attn, dim3(SS / QT, 1, BB), dim3(256), 0, stream, q, k, v, cm, cz, out0);
    hipLaunchKernelGGL(k4_stats, dim3(BB, NCH2), dim3(64), 0, stream, out0, pm2, pz2);
    hipLaunchKernelGGL(k5_combine2, dim3(1), dim3(256), 0, stream, pm2, pz2, m2, iz2);
    hipLaunchKernelGGL(k6_write, dim3(BB * SS * DD / 256), dim3(256), 0, stream, out0, m2, iz2, out1);
}

// Round 2
// 129.373 us; speedup vs baseline: 6.1764x; 6.1764x over previous
//
#include <hip/hip_runtime.h>
#include <math.h>

#define BB 4
#define SS 4096
#define DD 64
#define NCH2 32
#define QC2 (SS/NCH2)

typedef __attribute__((ext_vector_type(8))) short short8;
typedef __attribute__((ext_vector_type(4))) float f32x4;
typedef unsigned int u32;
typedef unsigned short ushort_t;

#define MFMA16(a,b,c) __builtin_amdgcn_mfma_f32_16x16x32_bf16((a),(b),(c),0,0,0)

static __device__ __forceinline__ unsigned short f2bf(float f) {
  union { float f; u32 u; } x; x.f = f;
  u32 r = (x.u + 0x7FFFu + ((x.u >> 16) & 1u)) >> 16;
  return (unsigned short)r;
}

static __device__ __forceinline__ void gload16(const void* g, void* l) {
  __builtin_amdgcn_global_load_lds((const __attribute__((address_space(1))) u32*)g,
                                   (__attribute__((address_space(3))) u32*)l, 16, 0, 0);
}

// ---------------- P0: convert Q,K -> bf16 (row-major, same layout)
__global__ __launch_bounds__(256) void p0_convert(
    const float* __restrict__ q, const float* __restrict__ k,
    ushort_t* __restrict__ QB, ushort_t* __restrict__ KB)
{
  const size_t i = (size_t)blockIdx.x * 256 + threadIdx.x;  // over BB*SS*DD/4
  float4 a = ((const float4*)q)[i];
  float4 c = ((const float4*)k)[i];
  ((ushort4*)QB)[i] = make_ushort4(f2bf(a.x), f2bf(a.y), f2bf(a.z), f2bf(a.w));
  ((ushort4*)KB)[i] = make_ushort4(f2bf(c.x), f2bf(c.y), f2bf(c.z), f2bf(c.w));
}

// ---------------- PA: Z[k] = sum_q exp(s_qk) via MFMA (C[k][q] orientation)
// grid (SS/64, 2, BB), 256 thr. Wave w owns k rows 16w..16w+15 of its 64-k tile.
__global__ __launch_bounds__(256) void pa_colsum(
    const ushort_t* __restrict__ QB, const ushort_t* __restrict__ KB,
    float* __restrict__ Zp)
{
  const int kb0 = blockIdx.x * 64;
  const int qch = blockIdx.y;
  const int b   = blockIdx.z;
  const int t = threadIdx.x, w = t >> 6, lane = t & 63;
  const int g = lane >> 4, r15 = lane & 15;
  const int r8 = lane >> 3, c8 = lane & 7;

  __shared__ alignas(16) char qbuf[2][64*128];

  short8 ak[2];
  {
    const ushort_t* p = KB + ((size_t)b * SS + kb0 + 16*w + r15) * DD;
#pragma unroll
    for (int dh = 0; dh < 2; ++dh) ak[dh] = *(const short8*)(p + 32*dh + 8*g);
  }

  // prologue stage
  {
    const int q0 = qch * 2048;
#pragma unroll
    for (int j = 0; j < 2; ++j) {
      const int rl = 16*w + 8*j + r8;
      const char* gsrc = (const char*)(QB + ((size_t)b*SS + q0 + rl)*DD) + 16*(c8 ^ r8);
      gload16(gsrc, qbuf[0] + (16*w + 8*j)*128);
    }
  }

  float z0=0.f, z1=0.f, z2=0.f, z3=0.f;
  const float inv = 1.0f / 64.0f;
  int cur = 0;
  for (int tt = 0; tt < 32; ++tt) {
    if (tt < 31) {
      const int q0 = qch*2048 + (tt+1)*64;
#pragma unroll
      for (int j = 0; j < 2; ++j) {
        const int rl = 16*w + 8*j + r8;
        const char* gsrc = (const char*)(QB + ((size_t)b*SS + q0 + rl)*DD) + 16*(c8 ^ r8);
        gload16(gsrc, qbuf[cur^1] + (16*w + 8*j)*128);
      }
      asm volatile("s_waitcnt vmcnt(2)" ::: "memory");
    } else {
      asm volatile("s_waitcnt vmcnt(0)" ::: "memory");
    }
    __builtin_amdgcn_s_barrier();

    const char* qb = qbuf[cur];
#pragma unroll
    for (int qt = 0; qt < 4; ++qt) {
      f32x4 acc = {0.f,0.f,0.f,0.f};
      const int qrow = 16*qt + r15;
      const char* base = qb + qrow*128;
#pragma unroll
      for (int dh = 0; dh < 2; ++dh) {
        short8 bq = *(const short8*)(base + 16*((4*dh + g) ^ (qrow & 7)));
        acc = MFMA16(ak[dh], bq, acc);
      }
      z0 += __expf(acc[0]*inv); z1 += __expf(acc[1]*inv);
      z2 += __expf(acc[2]*inv); z3 += __expf(acc[3]*inv);
    }
    __builtin_amdgcn_s_barrier();
    cur ^= 1;
  }
#pragma unroll
  for (int m = 1; m < 16; m <<= 1) {
    z0 += __shfl_xor(z0, m); z1 += __shfl_xor(z1, m);
    z2 += __shfl_xor(z2, m); z3 += __shfl_xor(z3, m);
  }
  if (r15 == 0) {
    float* dst = Zp + ((size_t)qch*BB + b)*SS + kb0 + 16*w + 4*g;
    dst[0]=z0; dst[1]=z1; dst[2]=z2; dst[3]=z3;
  }
}

// ---------------- P2: VT[b][d][s] = bf16( V[b][s][d] / Z[s] )
__global__ __launch_bounds__(256) void p2_vt(
    const float* __restrict__ v, const float* __restrict__ Zp,
    ushort_t* __restrict__ VT)
{
  const int k0 = blockIdx.x * 64;
  const int b  = blockIdx.y;
  const int t = threadIdx.x;
  __shared__ float vs[64][65];
  __shared__ float izs[64];
  {
    const int row = t >> 2, cq = (t & 3) * 16;
    const float* src = v + ((size_t)b*SS + k0 + row)*DD + cq;
#pragma unroll
    for (int i = 0; i < 4; ++i) {
      float4 x = ((const float4*)src)[i];
      vs[row][cq + 4*i + 0] = x.x; vs[row][cq + 4*i + 1] = x.y;
      vs[row][cq + 4*i + 2] = x.z; vs[row][cq + 4*i + 3] = x.w;
    }
  }
  if (t < 64) {
    float z = Zp[(size_t)b*SS + k0 + t] + Zp[((size_t)BB + b)*SS + k0 + t];
    izs[t] = 1.0f / z;
  }
  __syncthreads();
  const int d = t >> 2, ks = (t & 3) * 16;
  u32* dst = (u32*)VT + (((size_t)b*DD + d)*SS + k0 + ks)/2;
#pragma unroll
  for (int i = 0; i < 8; ++i) {
    float a0 = vs[ks + 2*i    ][d] * izs[ks + 2*i    ];
    float a1 = vs[ks + 2*i + 1][d] * izs[ks + 2*i + 1];
    dst[i] = (u32)f2bf(a0) | ((u32)f2bf(a1) << 16);
  }
}

// ---------------- PB: attn = exp(QK^T/64) * VT  (main MFMA pass)
// grid (SS/32, BB), 256 thr. Wave w: qsub=w&1 (16 rows), khalf=w>>1 (32 k-cols).
__global__ __launch_bounds__(256) void pb_attn(
    const ushort_t* __restrict__ QB, const ushort_t* __restrict__ KB,
    const ushort_t* __restrict__ VT, float* __restrict__ out0)
{
  const int q0 = blockIdx.x * 32;
  const int b  = blockIdx.y;
  const int t = threadIdx.x, w = t >> 6, lane = t & 63;
  const int g = lane >> 4, r15 = lane & 15;
  const int qsub = w & 1, khalf = w >> 1;
  const int r8 = lane >> 3, c8 = lane & 7;

  __shared__ alignas(16) char kbuf[2][64*128];
  __shared__ alignas(16) char vbuf[2][64*128];
  __shared__ alignas(16) ushort_t Plds[32*64];
  __shared__ float red[32*65];

  short8 aq[2];
  {
    const ushort_t* p = QB + ((size_t)b*SS + q0 + 16*qsub + r15) * DD;
#pragma unroll
    for (int dh = 0; dh < 2; ++dh) aq[dh] = *(const short8*)(p + 32*dh + 8*g);
  }

  f32x4 accA[4];
#pragma unroll
  for (int dt = 0; dt < 4; ++dt) accA[dt] = (f32x4){0.f,0.f,0.f,0.f};

  const float inv = 1.0f/64.0f;

  // prologue stage k-step 0
#pragma unroll
  for (int j = 0; j < 2; ++j) {
    const int rl = 16*w + 8*j + r8;
    const char* gk = (const char*)(KB + ((size_t)b*SS + rl)*DD) + 16*(c8 ^ r8);
    gload16(gk, kbuf[0] + (16*w+8*j)*128);
    const char* gv = (const char*)(VT + ((size_t)b*DD + rl)*SS) + 16*(c8 ^ r8);
    gload16(gv, vbuf[0] + (16*w+8*j)*128);
  }

  int cur = 0;
  for (int kt = 0; kt < 64; ++kt) {
    if (kt < 63) {
      const int k0n = (kt+1)*64;
#pragma unroll
      for (int j = 0; j < 2; ++j) {
        const int rl = 16*w + 8*j + r8;
        const char* gk = (const char*)(KB + ((size_t)b*SS + k0n + rl)*DD) + 16*(c8 ^ r8);
        gload16(gk, kbuf[cur^1] + (16*w+8*j)*128);
        const char* gv = (const char*)(VT + (((size_t)b*DD + rl)*SS + k0n)) + 16*(c8 ^ r8);
        gload16(gv, vbuf[cur^1] + (16*w+8*j)*128);
      }
      asm volatile("s_waitcnt vmcnt(4)" ::: "memory");
    } else {
      asm volatile("s_waitcnt vmcnt(0)" ::: "memory");
    }
    __builtin_amdgcn_s_barrier();

    const char* kb = kbuf[cur];
    const char* vb = vbuf[cur];

    // QK^T for this wave's 16 q rows x 32 k cols
    f32x4 accs[2];
#pragma unroll
    for (int ct = 0; ct < 2; ++ct) {
      accs[ct] = (f32x4){0.f,0.f,0.f,0.f};
      const int krow = 32*khalf + 16*ct + r15;
      const char* base = kb + krow*128;
#pragma unroll
      for (int dh = 0; dh < 2; ++dh) {
        short8 bk = *(const short8*)(base + 16*((4*dh+g) ^ (krow&7)));
        accs[ct] = MFMA16(aq[dh], bk, accs[ct]);
      }
    }
    // exp -> P (wave-private quarter; swizzled rows)
#pragma unroll
    for (int ct = 0; ct < 2; ++ct) {
#pragma unroll
      for (int rr = 0; rr < 4; ++rr) {
        const int qrow = 16*qsub + 4*g + rr;
        const int kcol = 32*khalf + 16*ct + r15;
        Plds[qrow*64 + (kcol ^ ((qrow&7)<<3))] = f2bf(__expf(accs[ct][rr]*inv));
      }
    }
    // PV partial over this wave's khalf
    {
      const int qrow = 16*qsub + r15;
      short8 ap = *(const short8*)((const char*)Plds + qrow*128 + 16*((4*khalf+g) ^ (qrow&7)));
#pragma unroll
      for (int dt = 0; dt < 4; ++dt) {
        const int drow = 16*dt + r15;
        short8 bv = *(const short8*)(vb + drow*128 + 16*((4*khalf+g) ^ (drow&7)));
        accA[dt] = MFMA16(ap, bv, accA[dt]);
      }
    }
    __builtin_amdgcn_s_barrier();
    cur ^= 1;
  }

  __syncthreads();
  if (w >= 2) {
#pragma unroll
    for (int dt = 0; dt < 4; ++dt)
#pragma unroll
      for (int rr = 0; rr < 4; ++rr)
        red[(16*qsub + 4*g + rr)*65 + 16*dt + r15] = accA[dt][rr];
  }
  __syncthreads();
  if (w < 2) {
#pragma unroll
    for (int dt = 0; dt < 4; ++dt)
#pragma unroll
      for (int rr = 0; rr < 4; ++rr) {
        const int qq = 16*qsub + 4*g + rr;
        const int d  = 16*dt + r15;
        out0[((size_t)b*SS + q0 + qq)*DD + d] = accA[dt][rr] + red[qq*65 + d];
      }
  }
}

// ---------------- K4: partial stats over q of attn, per (b,d)
__global__ __launch_bounds__(64) void k4_stats(
    const float* __restrict__ attn, float* __restrict__ pm2, float* __restrict__ pz2)
{
  const int b = blockIdx.x, ch = blockIdx.y;
  const int d = threadIdx.x;
  float m = -1e30f, z = 0.f;
  for (int qq = ch * QC2; qq < (ch + 1) * QC2; ++qq) {
    float a = attn[((size_t)b * SS + qq) * DD + d];
    float mn = fmaxf(m, a);
    z = z * __expf(m - mn) + __expf(a - mn);
    m = mn;
  }
  pm2[(ch * BB + b) * DD + d] = m;
  pz2[(ch * BB + b) * DD + d] = z;
}

// ---------------- K5: combine -> m2, 1/Z2
__global__ __launch_bounds__(256) void k5_combine2(
    const float* __restrict__ pm2, const float* __restrict__ pz2,
    float* __restrict__ m2, float* __restrict__ iz2)
{
  const int idx = threadIdx.x;
  float m = -1e30f;
#pragma unroll
  for (int c = 0; c < NCH2; ++c) m = fmaxf(m, pm2[c * BB * DD + idx]);
  float z = 0.f;
#pragma unroll
  for (int c = 0; c < NCH2; ++c) z += pz2[c * BB * DD + idx] * __expf(pm2[c * BB * DD + idx] - m);
  m2[idx] = m;
  iz2[idx] = 1.0f / z;
}

// ---------------- K6: attn_w = exp(attn - m2) * iz2
__global__ __launch_bounds__(256) void k6_write(
    const float* __restrict__ attn, const float* __restrict__ m2,
    const float* __restrict__ iz2, float* __restrict__ out1)
{
  const size_t i = (size_t)blockIdx.x * 256 + threadIdx.x;
  const int b = (int)(i / ((size_t)SS * DD));
  const int d = (int)(i % DD);
  const int cidx = b * DD + d;
  out1[i] = __expf(attn[i] - m2[cidx]) * iz2[cidx];
}

extern "C" void kernel_launch(void* const* d_in, const int* in_sizes, int n_in,
                              void* d_out, int out_size, void* d_ws, size_t ws_size,
                              hipStream_t stream) {
  const float* q = (const float*)d_in[0];
  const float* k = (const float*)d_in[1];
  const float* v = (const float*)d_in[2];
  float* out0 = (float*)d_out;
  float* out1 = out0 + (size_t)BB * SS * DD;

  // QB/KB scratch lives in the out1 region (overwritten by k6 at the end).
  ushort_t* QB = (ushort_t*)out1;
  ushort_t* KB = QB + (size_t)BB * SS * DD;

  float* ws = (float*)d_ws;
  ushort_t* VT = (ushort_t*)ws;                               // BB*DD*SS bf16
  float* Zp  = (float*)(VT + (size_t)BB * DD * SS);           // 2*BB*SS
  float* pm2 = Zp + (size_t)2 * BB * SS;
  float* pz2 = pm2 + (size_t)NCH2 * BB * DD;
  float* m2  = pz2 + (size_t)NCH2 * BB * DD;
  float* iz2 = m2 + (size_t)BB * DD;

  hipLaunchKernelGGL(p0_convert, dim3(BB*SS*DD/4/256), dim3(256), 0, stream, q, k, QB, KB);
  hipLaunchKernelGGL(pa_colsum, dim3(SS/64, 2, BB), dim3(256), 0, stream, QB, KB, Zp);
  hipLaunchKernelGGL(p2_vt, dim3(SS/64, BB), dim3(256), 0, stream, v, Zp, VT);
  hipLaunchKernelGGL(pb_attn, dim3(SS/32, BB), dim3(256), 0, stream, QB, KB, VT, out0);
  hipLaunchKernelGGL(k4_stats, dim3(BB, NCH2), dim3(64), 0, stream, out0, pm2, pz2);
  hipLaunchKernelGGL(k5_combine2, dim3(1), dim3(256), 0, stream, pm2, pz2, m2, iz2);
  hipLaunchKernelGGL(k6_write, dim3(BB*SS*DD/256), dim3(256), 0, stream, out0, m2, iz2, out1);
}

// Round 3
// 99.143 us; speedup vs baseline: 8.0597x; 1.3049x over previous
//
#include <hip/hip_runtime.h>
#include <hip/hip_bf16.h>
#include <math.h>

#define BB 4
#define SS 4096
#define DD 64

typedef __attribute__((ext_vector_type(8))) short short8;
typedef __attribute__((ext_vector_type(4))) float f32x4;
typedef __attribute__((ext_vector_type(2))) unsigned int u32x2;
typedef unsigned int u32;
typedef unsigned short ushort_t;

#define MFMA16(a,b,c) __builtin_amdgcn_mfma_f32_16x16x32_bf16((a),(b),(c),0,0,0)
// exp(s/64) == exp2(s * C2SC)
#define C2SC 0.022542110700140054f

static __device__ __forceinline__ unsigned short f2bf(float f) {
  union { float f; u32 u; } x; x.f = f;
  u32 r = (x.u + 0x7FFFu + ((x.u >> 16) & 1u)) >> 16;
  return (unsigned short)r;
}

static __device__ __forceinline__ u32 pk2(float a, float b) {
  __hip_bfloat16 lo = __float2bfloat16(a);
  __hip_bfloat16 hi = __float2bfloat16(b);
  unsigned short ls, hs;
  __builtin_memcpy(&ls, &lo, 2); __builtin_memcpy(&hs, &hi, 2);
  return (u32)ls | ((u32)hs << 16);
}

static __device__ __forceinline__ void gload16(const void* g, void* l) {
  __builtin_amdgcn_global_load_lds((const __attribute__((address_space(1))) u32*)g,
                                   (__attribute__((address_space(3))) u32*)l, 16, 0, 0);
}

// ---------------- P0: convert Q,K -> bf16; zero out0 and z2
__global__ __launch_bounds__(256) void p0_convert(
    const float* __restrict__ q, const float* __restrict__ k,
    ushort_t* __restrict__ QB, ushort_t* __restrict__ KB,
    float* __restrict__ out0, float* __restrict__ z2)
{
  const size_t i = (size_t)blockIdx.x * 256 + threadIdx.x;  // over BB*SS*DD/4
  float4 a = ((const float4*)q)[i];
  float4 c = ((const float4*)k)[i];
  ((ushort4*)QB)[i] = make_ushort4(f2bf(a.x), f2bf(a.y), f2bf(a.z), f2bf(a.w));
  ((ushort4*)KB)[i] = make_ushort4(f2bf(c.x), f2bf(c.y), f2bf(c.z), f2bf(c.w));
  ((float4*)out0)[i] = make_float4(0.f, 0.f, 0.f, 0.f);
  if (blockIdx.x == 0) z2[threadIdx.x] = 0.f;
}

// ---------------- PA: Z[k] = sum_q exp(s_qk) via MFMA
// grid (SS/64, 2, BB), 256 thr. Wave w owns k rows 16w..16w+15 of its 64-k tile.
__global__ __launch_bounds__(256) void pa_colsum(
    const ushort_t* __restrict__ QB, const ushort_t* __restrict__ KB,
    float* __restrict__ Zp)
{
  const int kb0 = blockIdx.x * 64;
  const int qch = blockIdx.y;
  const int b   = blockIdx.z;
  const int t = threadIdx.x, w = t >> 6, lane = t & 63;
  const int g = lane >> 4, r15 = lane & 15;
  const int r8 = lane >> 3, c8 = lane & 7;

  __shared__ alignas(16) char qbuf[2][64*128];

  short8 ak[2];
  {
    const ushort_t* p = KB + ((size_t)b * SS + kb0 + 16*w + r15) * DD;
#pragma unroll
    for (int dh = 0; dh < 2; ++dh) ak[dh] = *(const short8*)(p + 32*dh + 8*g);
  }

  // prologue stage tile 0
  {
    const int q0 = qch * 2048;
#pragma unroll
    for (int j = 0; j < 2; ++j) {
      const int rl = 16*w + 8*j + r8;
      const char* gsrc = (const char*)(QB + ((size_t)b*SS + q0 + rl)*DD) + 16*(c8 ^ r8);
      gload16(gsrc, qbuf[0] + (16*w + 8*j)*128);
    }
  }
  asm volatile("s_waitcnt vmcnt(0)" ::: "memory");
  __syncthreads();

  float z0=0.f, z1=0.f, z2v=0.f, z3=0.f;
  int cur = 0;
  for (int tt = 0; tt < 32; ++tt) {
    if (tt < 31) {
      const int q0 = qch*2048 + (tt+1)*64;
#pragma unroll
      for (int j = 0; j < 2; ++j) {
        const int rl = 16*w + 8*j + r8;
        const char* gsrc = (const char*)(QB + ((size_t)b*SS + q0 + rl)*DD) + 16*(c8 ^ r8);
        gload16(gsrc, qbuf[cur^1] + (16*w + 8*j)*128);
      }
    }
    const char* qb = qbuf[cur];
#pragma unroll
    for (int qt = 0; qt < 4; ++qt) {
      f32x4 acc = {0.f,0.f,0.f,0.f};
      const int qrow = 16*qt + r15;
      const char* base = qb + qrow*128;
#pragma unroll
      for (int dh = 0; dh < 2; ++dh) {
        short8 bq = *(const short8*)(base + 16*((4*dh + g) ^ (qrow & 7)));
        acc = MFMA16(ak[dh], bq, acc);
      }
      z0 += exp2f(acc[0]*C2SC); z1 += exp2f(acc[1]*C2SC);
      z2v += exp2f(acc[2]*C2SC); z3 += exp2f(acc[3]*C2SC);
    }
    asm volatile("s_waitcnt vmcnt(0)" ::: "memory");
    __syncthreads();
    cur ^= 1;
  }
#pragma unroll
  for (int m = 1; m < 16; m <<= 1) {
    z0 += __shfl_xor(z0, m); z1 += __shfl_xor(z1, m);
    z2v += __shfl_xor(z2v, m); z3 += __shfl_xor(z3, m);
  }
  if (r15 == 0) {
    float* dst = Zp + ((size_t)qch*BB + b)*SS + kb0 + 16*w + 4*g;
    dst[0]=z0; dst[1]=z1; dst[2]=z2v; dst[3]=z3;
  }
}

// ---------------- P2: VT[b][d][s] = bf16( V[b][s][d] / Z[s] )
__global__ __launch_bounds__(256) void p2_vt(
    const float* __restrict__ v, const float* __restrict__ Zp,
    ushort_t* __restrict__ VT)
{
  const int k0 = blockIdx.x * 64;
  const int b  = blockIdx.y;
  const int t = threadIdx.x;
  __shared__ float vs[64][65];
  __shared__ float izs[64];
  {
    const int row = t >> 2, cq = (t & 3) * 16;
    const float* src = v + ((size_t)b*SS + k0 + row)*DD + cq;
#pragma unroll
    for (int i = 0; i < 4; ++i) {
      float4 x = ((const float4*)src)[i];
      vs[row][cq + 4*i + 0] = x.x; vs[row][cq + 4*i + 1] = x.y;
      vs[row][cq + 4*i + 2] = x.z; vs[row][cq + 4*i + 3] = x.w;
    }
  }
  if (t < 64) {
    float z = Zp[(size_t)b*SS + k0 + t] + Zp[((size_t)BB + b)*SS + k0 + t];
    izs[t] = 1.0f / z;
  }
  __syncthreads();
  const int d = t >> 2, ks = (t & 3) * 16;
  u32* dst = (u32*)VT + (((size_t)b*DD + d)*SS + k0 + ks)/2;
#pragma unroll
  for (int i = 0; i < 8; ++i) {
    float a0 = vs[ks + 2*i    ][d] * izs[ks + 2*i    ];
    float a1 = vs[ks + 2*i + 1][d] * izs[ks + 2*i + 1];
    dst[i] = (u32)f2bf(a0) | ((u32)f2bf(a1) << 16);
  }
}

// ---------------- PB: attn += exp(QK^T/64) * VT over this block's k-half
// grid (SS/64, 2, BB), 256 thr. Wave w owns q rows 16w..16w+15; full 64-k tile.
__global__ __launch_bounds__(256) void pb_attn(
    const ushort_t* __restrict__ QB, const ushort_t* __restrict__ KB,
    const ushort_t* __restrict__ VT, float* __restrict__ out0)
{
  const int q0 = blockIdx.x * 64;
  const int kbase = blockIdx.y * 2048;
  const int b  = blockIdx.z;
  const int t = threadIdx.x, w = t >> 6, lane = t & 63;
  const int g = lane >> 4, r15 = lane & 15;
  const int r8 = lane >> 3, c8 = lane & 7;

  __shared__ alignas(16) char kbuf[2][64*128];
  __shared__ alignas(16) char vbuf[2][64*128];
  __shared__ alignas(16) char plds[4][16*128];   // per-wave P[16 q][64 k], swizzled

  // Q fragments (B-operand): lane holds Q[q0+16w+r15][32dh+8g+j]
  short8 aq[2];
  {
    const ushort_t* p = QB + ((size_t)b*SS + q0 + 16*w + r15) * DD;
#pragma unroll
    for (int dh = 0; dh < 2; ++dh) aq[dh] = *(const short8*)(p + 32*dh + 8*g);
  }

  // prologue stage k-tile 0
#pragma unroll
  for (int j = 0; j < 2; ++j) {
    const int rl = 16*w + 8*j + r8;
    const char* gk = (const char*)(KB + ((size_t)b*SS + kbase + rl)*DD) + 16*(c8 ^ r8);
    gload16(gk, kbuf[0] + (16*w+8*j)*128);
    const char* gv = (const char*)(VT + ((size_t)b*DD + rl)*SS + kbase) + 16*(c8 ^ r8);
    gload16(gv, vbuf[0] + (16*w+8*j)*128);
  }
  asm volatile("s_waitcnt vmcnt(0)" ::: "memory");
  __syncthreads();

  f32x4 accA[4];
#pragma unroll
  for (int dt = 0; dt < 4; ++dt) accA[dt] = (f32x4){0.f,0.f,0.f,0.f};

  char* pw = plds[w];
  int cur = 0;
  for (int kt = 0; kt < 32; ++kt) {
    if (kt < 31) {
      const int kc = kbase + (kt+1)*64;
#pragma unroll
      for (int j = 0; j < 2; ++j) {
        const int rl = 16*w + 8*j + r8;
        const char* gk = (const char*)(KB + ((size_t)b*SS + kc + rl)*DD) + 16*(c8 ^ r8);
        gload16(gk, kbuf[cur^1] + (16*w+8*j)*128);
        const char* gv = (const char*)(VT + ((size_t)b*DD + rl)*SS + kc) + 16*(c8 ^ r8);
        gload16(gv, vbuf[cur^1] + (16*w+8*j)*128);
      }
    }
    const char* kb = kbuf[cur];
    const char* vb = vbuf[cur];

    // QK^T swapped: A = K-frag (LDS), B = Q-frag (regs) -> lane holds
    // P[k=16ct+4g+rr][q=r15]: 4 consecutive k for one q -> packed b64 write.
#pragma unroll
    for (int ct = 0; ct < 4; ++ct) {
      f32x4 accs = {0.f,0.f,0.f,0.f};
      const int krow = 16*ct + r15;
      const char* base = kb + krow*128;
#pragma unroll
      for (int dh = 0; dh < 2; ++dh) {
        short8 ak = *(const short8*)(base + 16*((4*dh+g) ^ (krow&7)));
        accs = MFMA16(ak, aq[dh], accs);
      }
      u32 p01 = pk2(exp2f(accs[0]*C2SC), exp2f(accs[1]*C2SC));
      u32 p23 = pk2(exp2f(accs[2]*C2SC), exp2f(accs[3]*C2SC));
      const u32 off = ((u32)(32*ct + 8*g)) ^ (((u32)(r15 & 7)) << 4);
      *(u32x2*)(pw + r15*128 + off) = (u32x2){p01, p23};
    }

    // PV: A = P-frag (own wave's), B = V-frag
#pragma unroll
    for (int ks = 0; ks < 2; ++ks) {
      const u32 poff = ((u32)(64*ks + 16*g)) ^ (((u32)(r15 & 7)) << 4);
      short8 ap = *(const short8*)(pw + r15*128 + poff);
#pragma unroll
      for (int dt = 0; dt < 4; ++dt) {
        const int drow = 16*dt + r15;
        short8 bv = *(const short8*)(vb + drow*128 + 16*((4*ks+g) ^ (drow&7)));
        accA[dt] = MFMA16(ap, bv, accA[dt]);
      }
    }
    asm volatile("s_waitcnt vmcnt(0)" ::: "memory");
    __syncthreads();
    cur ^= 1;
  }

#pragma unroll
  for (int dt = 0; dt < 4; ++dt)
#pragma unroll
    for (int rr = 0; rr < 4; ++rr)
      atomicAdd(&out0[((size_t)b*SS + q0 + 16*w + 4*g + rr)*DD + 16*dt + r15],
                accA[dt][rr]);
}

// ---------------- K4F: column sum of exp(attn) over q -> z2 (atomic)
// grid (BB, SS/64), 256 thr.
__global__ __launch_bounds__(256) void k4f(
    const float* __restrict__ attn, float* __restrict__ z2)
{
  const int b = blockIdx.x;
  const int q0 = blockIdx.y * 64;
  const int t = threadIdx.x;
  const int d = t & 63, rg = t >> 6;
  float ze = 0.f;
#pragma unroll
  for (int i = 0; i < 16; ++i) {
    float a = attn[((size_t)b*SS + q0 + 4*i + rg)*DD + d];
    ze += __expf(a);
  }
  __shared__ float red[4][64];
  red[rg][d] = ze;
  __syncthreads();
  if (t < 64)
    atomicAdd(&z2[b*DD + t], red[0][t] + red[1][t] + red[2][t] + red[3][t]);
}

// ---------------- K6: attn_w = exp(attn) / z2
__global__ __launch_bounds__(256) void k6w(
    const float* __restrict__ attn, const float* __restrict__ z2,
    float* __restrict__ out1)
{
  const size_t i = (size_t)blockIdx.x * 256 + threadIdx.x;
  const int b = (int)(i >> 18);        // SS*DD = 262144
  const int d = (int)(i & 63);
  out1[i] = __expf(attn[i]) / z2[b*DD + d];
}

extern "C" void kernel_launch(void* const* d_in, const int* in_sizes, int n_in,
                              void* d_out, int out_size, void* d_ws, size_t ws_size,
                              hipStream_t stream) {
  const float* q = (const float*)d_in[0];
  const float* k = (const float*)d_in[1];
  const float* v = (const float*)d_in[2];
  float* out0 = (float*)d_out;
  float* out1 = out0 + (size_t)BB * SS * DD;

  // bf16 Q/K scratch lives in the out1 region (overwritten by k6w at the end).
  ushort_t* QB = (ushort_t*)out1;                 // 2 MB
  ushort_t* KB = QB + (size_t)BB * SS * DD;       // 2 MB

  float* ws = (float*)d_ws;
  ushort_t* VT = (ushort_t*)ws;                              // 2 MB bf16
  float* Zp = (float*)(VT + (size_t)BB * DD * SS);           // 2*BB*SS
  float* z2 = Zp + (size_t)2 * BB * SS;                      // BB*DD

  hipLaunchKernelGGL(p0_convert, dim3(BB*SS*DD/4/256), dim3(256), 0, stream, q, k, QB, KB, out0, z2);
  hipLaunchKernelGGL(pa_colsum, dim3(SS/64, 2, BB), dim3(256), 0, stream, QB, KB, Zp);
  hipLaunchKernelGGL(p2_vt, dim3(SS/64, BB), dim3(256), 0, stream, v, Zp, VT);
  hipLaunchKernelGGL(pb_attn, dim3(SS/64, 2, BB), dim3(256), 0, stream, QB, KB, VT, out0);
  hipLaunchKernelGGL(k4f, dim3(BB, SS/64), dim3(256), 0, stream, out0, z2);
  hipLaunchKernelGGL(k6w, dim3(BB*SS*DD/256), dim3(256), 0, stream, out0, z2, out1);
}

// Round 4
// 83.231 us; speedup vs baseline: 9.6006x; 1.1912x over previous
//
#include <hip/hip_runtime.h>
#include <hip/hip_bf16.h>
#include <math.h>

#define BB 4
#define SS 4096
#define DD 64
#define KSPLIT 4      // pb k-splits
#define QSPLIT 8      // pa q-splits

typedef __attribute__((ext_vector_type(8))) short short8;
typedef __attribute__((ext_vector_type(4))) float f32x4;
typedef __attribute__((ext_vector_type(2))) unsigned int u32x2;
typedef unsigned int u32;
typedef unsigned short ushort_t;

#define MFMA16(a,b,c) __builtin_amdgcn_mfma_f32_16x16x32_bf16((a),(b),(c),0,0,0)
// exp(s/64) == exp2(s * C2SC)
#define C2SC 0.022542110700140054f

static __device__ __forceinline__ unsigned short f2bf(float f) {
  union { float f; u32 u; } x; x.f = f;
  u32 r = (x.u + 0x7FFFu + ((x.u >> 16) & 1u)) >> 16;
  return (unsigned short)r;
}

static __device__ __forceinline__ u32 pk2(float a, float b) {
  __hip_bfloat16 lo = __float2bfloat16(a);
  __hip_bfloat16 hi = __float2bfloat16(b);
  unsigned short ls, hs;
  __builtin_memcpy(&ls, &lo, 2); __builtin_memcpy(&hs, &hi, 2);
  return (u32)ls | ((u32)hs << 16);
}

static __device__ __forceinline__ void gload16(const void* g, void* l) {
  __builtin_amdgcn_global_load_lds((const __attribute__((address_space(1))) u32*)g,
                                   (__attribute__((address_space(3))) u32*)l, 16, 0, 0);
}

// ---------------- P0: convert Q,K -> bf16; zero out0 and z2
__global__ __launch_bounds__(256) void p0_convert(
    const float* __restrict__ q, const float* __restrict__ k,
    ushort_t* __restrict__ QB, ushort_t* __restrict__ KB,
    float* __restrict__ out0, float* __restrict__ z2)
{
  const size_t i = (size_t)blockIdx.x * 256 + threadIdx.x;  // over BB*SS*DD/4
  float4 a = ((const float4*)q)[i];
  float4 c = ((const float4*)k)[i];
  ((ushort4*)QB)[i] = make_ushort4(f2bf(a.x), f2bf(a.y), f2bf(a.z), f2bf(a.w));
  ((ushort4*)KB)[i] = make_ushort4(f2bf(c.x), f2bf(c.y), f2bf(c.z), f2bf(c.w));
  ((float4*)out0)[i] = make_float4(0.f, 0.f, 0.f, 0.f);
  if (blockIdx.x == 0) z2[threadIdx.x] = 0.f;
}

// ---------------- PA: Z[k] partial = sum_{q in chunk} exp(s_qk) via MFMA
// grid (SS/64, QSPLIT, BB), 256 thr. Wave w owns k rows 16w..16w+15.
__global__ __launch_bounds__(256) void pa_colsum(
    const ushort_t* __restrict__ QB, const ushort_t* __restrict__ KB,
    float* __restrict__ Zp)
{
  const int kb0 = blockIdx.x * 64;
  const int qch = blockIdx.y;
  const int b   = blockIdx.z;
  const int t = threadIdx.x, w = t >> 6, lane = t & 63;
  const int g = lane >> 4, r15 = lane & 15;
  const int r8 = lane >> 3, c8 = lane & 7;
  const int QCH = SS / QSPLIT;         // 512
  const int NT = QCH / 64;             // 8

  __shared__ alignas(16) char qbuf[2][64*128];

  short8 ak[2];
  {
    const ushort_t* p = KB + ((size_t)b * SS + kb0 + 16*w + r15) * DD;
#pragma unroll
    for (int dh = 0; dh < 2; ++dh) ak[dh] = *(const short8*)(p + 32*dh + 8*g);
  }

  // prologue stage tile 0
  {
    const int q0 = qch * QCH;
#pragma unroll
    for (int j = 0; j < 2; ++j) {
      const int rl = 16*w + 8*j + r8;
      const char* gsrc = (const char*)(QB + ((size_t)b*SS + q0 + rl)*DD) + 16*(c8 ^ r8);
      gload16(gsrc, qbuf[0] + (16*w + 8*j)*128);
    }
  }
  asm volatile("s_waitcnt vmcnt(0)" ::: "memory");
  __syncthreads();

  float z0=0.f, z1=0.f, z2v=0.f, z3=0.f;
  int cur = 0;
  for (int tt = 0; tt < NT; ++tt) {
    if (tt < NT-1) {
      const int q0 = qch*QCH + (tt+1)*64;
#pragma unroll
      for (int j = 0; j < 2; ++j) {
        const int rl = 16*w + 8*j + r8;
        const char* gsrc = (const char*)(QB + ((size_t)b*SS + q0 + rl)*DD) + 16*(c8 ^ r8);
        gload16(gsrc, qbuf[cur^1] + (16*w + 8*j)*128);
      }
    }
    const char* qb = qbuf[cur];
#pragma unroll
    for (int qt = 0; qt < 4; ++qt) {
      f32x4 acc = {0.f,0.f,0.f,0.f};
      const int qrow = 16*qt + r15;
      const char* base = qb + qrow*128;
#pragma unroll
      for (int dh = 0; dh < 2; ++dh) {
        short8 bq = *(const short8*)(base + 16*((4*dh + g) ^ (qrow & 7)));
        acc = MFMA16(ak[dh], bq, acc);
      }
      z0 += exp2f(acc[0]*C2SC); z1 += exp2f(acc[1]*C2SC);
      z2v += exp2f(acc[2]*C2SC); z3 += exp2f(acc[3]*C2SC);
    }
    asm volatile("s_waitcnt vmcnt(0)" ::: "memory");
    __syncthreads();
    cur ^= 1;
  }
#pragma unroll
  for (int m = 1; m < 16; m <<= 1) {
    z0 += __shfl_xor(z0, m); z1 += __shfl_xor(z1, m);
    z2v += __shfl_xor(z2v, m); z3 += __shfl_xor(z3, m);
  }
  if (r15 == 0) {
    float* dst = Zp + ((size_t)qch*BB + b)*SS + kb0 + 16*w + 4*g;
    dst[0]=z0; dst[1]=z1; dst[2]=z2v; dst[3]=z3;
  }
}

// ---------------- P2: VT[b][d][s] = bf16( V[b][s][d] / Z[s] )
__global__ __launch_bounds__(256) void p2_vt(
    const float* __restrict__ v, const float* __restrict__ Zp,
    ushort_t* __restrict__ VT)
{
  const int k0 = blockIdx.x * 64;
  const int b  = blockIdx.y;
  const int t = threadIdx.x;
  __shared__ float vs[64][65];
  __shared__ float izs[64];
  {
    const int row = t >> 2, cq = (t & 3) * 16;
    const float* src = v + ((size_t)b*SS + k0 + row)*DD + cq;
#pragma unroll
    for (int i = 0; i < 4; ++i) {
      float4 x = ((const float4*)src)[i];
      vs[row][cq + 4*i + 0] = x.x; vs[row][cq + 4*i + 1] = x.y;
      vs[row][cq + 4*i + 2] = x.z; vs[row][cq + 4*i + 3] = x.w;
    }
  }
  if (t < 64) {
    float z = 0.f;
#pragma unroll
    for (int c = 0; c < QSPLIT; ++c)
      z += Zp[((size_t)c*BB + b)*SS + k0 + t];
    izs[t] = 1.0f / z;
  }
  __syncthreads();
  const int d = t >> 2, ks = (t & 3) * 16;
  u32* dst = (u32*)VT + (((size_t)b*DD + d)*SS + k0 + ks)/2;
#pragma unroll
  for (int i = 0; i < 8; ++i) {
    float a0 = vs[ks + 2*i    ][d] * izs[ks + 2*i    ];
    float a1 = vs[ks + 2*i + 1][d] * izs[ks + 2*i + 1];
    dst[i] = (u32)f2bf(a0) | ((u32)f2bf(a1) << 16);
  }
}

// ---------------- PB: attn += exp(QK^T/64) * VT over this block's k-quarter
// grid (SS/64, KSPLIT, BB), 256 thr. Wave w owns q rows 16w..16w+15; full 64-k tile.
__global__ __launch_bounds__(256) void pb_attn(
    const ushort_t* __restrict__ QB, const ushort_t* __restrict__ KB,
    const ushort_t* __restrict__ VT, float* __restrict__ out0)
{
  const int q0 = blockIdx.x * 64;
  const int kbase = blockIdx.y * (SS / KSPLIT);
  const int b  = blockIdx.z;
  const int t = threadIdx.x, w = t >> 6, lane = t & 63;
  const int g = lane >> 4, r15 = lane & 15;
  const int r8 = lane >> 3, c8 = lane & 7;
  const int NT = SS / KSPLIT / 64;     // 16

  __shared__ alignas(16) char kbuf[2][64*128];
  __shared__ alignas(16) char vbuf[2][64*128];
  __shared__ alignas(16) char plds[4][16*128];   // per-wave P[16 q][64 k], swizzled

  // Q fragments (B-operand): lane holds Q[q0+16w+r15][32dh+8g+j]
  short8 aq[2];
  {
    const ushort_t* p = QB + ((size_t)b*SS + q0 + 16*w + r15) * DD;
#pragma unroll
    for (int dh = 0; dh < 2; ++dh) aq[dh] = *(const short8*)(p + 32*dh + 8*g);
  }

  // prologue stage k-tile 0
#pragma unroll
  for (int j = 0; j < 2; ++j) {
    const int rl = 16*w + 8*j + r8;
    const char* gk = (const char*)(KB + ((size_t)b*SS + kbase + rl)*DD) + 16*(c8 ^ r8);
    gload16(gk, kbuf[0] + (16*w+8*j)*128);
    const char* gv = (const char*)(VT + ((size_t)b*DD + rl)*SS + kbase) + 16*(c8 ^ r8);
    gload16(gv, vbuf[0] + (16*w+8*j)*128);
  }
  asm volatile("s_waitcnt vmcnt(0)" ::: "memory");
  __syncthreads();

  f32x4 accA[4];
#pragma unroll
  for (int dt = 0; dt < 4; ++dt) accA[dt] = (f32x4){0.f,0.f,0.f,0.f};

  char* pw = plds[w];
  int cur = 0;
  for (int kt = 0; kt < NT; ++kt) {
    if (kt < NT-1) {
      const int kc = kbase + (kt+1)*64;
#pragma unroll
      for (int j = 0; j < 2; ++j) {
        const int rl = 16*w + 8*j + r8;
        const char* gk = (const char*)(KB + ((size_t)b*SS + kc + rl)*DD) + 16*(c8 ^ r8);
        gload16(gk, kbuf[cur^1] + (16*w+8*j)*128);
        const char* gv = (const char*)(VT + ((size_t)b*DD + rl)*SS + kc) + 16*(c8 ^ r8);
        gload16(gv, vbuf[cur^1] + (16*w+8*j)*128);
      }
    }
    const char* kb = kbuf[cur];
    const char* vb = vbuf[cur];

    // QK^T swapped: A = K-frag (LDS), B = Q-frag (regs) -> lane holds
    // P[k=16ct+4g+rr][q=r15]: 4 consecutive k for one q -> packed b64 write.
#pragma unroll
    for (int ct = 0; ct < 4; ++ct) {
      f32x4 accs = {0.f,0.f,0.f,0.f};
      const int krow = 16*ct + r15;
      const char* base = kb + krow*128;
#pragma unroll
      for (int dh = 0; dh < 2; ++dh) {
        short8 ak = *(const short8*)(base + 16*((4*dh+g) ^ (krow&7)));
        accs = MFMA16(ak, aq[dh], accs);
      }
      u32 p01 = pk2(exp2f(accs[0]*C2SC), exp2f(accs[1]*C2SC));
      u32 p23 = pk2(exp2f(accs[2]*C2SC), exp2f(accs[3]*C2SC));
      const u32 off = ((u32)(32*ct + 8*g)) ^ (((u32)(r15 & 7)) << 4);
      *(u32x2*)(pw + r15*128 + off) = (u32x2){p01, p23};
    }

    // PV: A = P-frag (own wave's), B = V-frag
#pragma unroll
    for (int ks = 0; ks < 2; ++ks) {
      const u32 poff = ((u32)(64*ks + 16*g)) ^ (((u32)(r15 & 7)) << 4);
      short8 ap = *(const short8*)(pw + r15*128 + poff);
#pragma unroll
      for (int dt = 0; dt < 4; ++dt) {
        const int drow = 16*dt + r15;
        short8 bv = *(const short8*)(vb + drow*128 + 16*((4*ks+g) ^ (drow&7)));
        accA[dt] = MFMA16(ap, bv, accA[dt]);
      }
    }
    asm volatile("s_waitcnt vmcnt(0)" ::: "memory");
    __syncthreads();
    cur ^= 1;
  }

#pragma unroll
  for (int dt = 0; dt < 4; ++dt)
#pragma unroll
    for (int rr = 0; rr < 4; ++rr)
      atomicAdd(&out0[((size_t)b*SS + q0 + 16*w + 4*g + rr)*DD + 16*dt + r15],
                accA[dt][rr]);
}

// ---------------- K4F: column sum of exp(attn) over q -> z2 (atomic)
// grid (BB, SS/64), 256 thr.
__global__ __launch_bounds__(256) void k4f(
    const float* __restrict__ attn, float* __restrict__ z2)
{
  const int b = blockIdx.x;
  const int q0 = blockIdx.y * 64;
  const int t = threadIdx.x;
  const int d = t & 63, rg = t >> 6;
  float ze = 0.f;
#pragma unroll
  for (int i = 0; i < 16; ++i) {
    float a = attn[((size_t)b*SS + q0 + 4*i + rg)*DD + d];
    ze += __expf(a);
  }
  __shared__ float red[4][64];
  red[rg][d] = ze;
  __syncthreads();
  if (t < 64)
    atomicAdd(&z2[b*DD + t], red[0][t] + red[1][t] + red[2][t] + red[3][t]);
}

// ---------------- K6: attn_w = exp(attn) / z2
__global__ __launch_bounds__(256) void k6w(
    const float* __restrict__ attn, const float* __restrict__ z2,
    float* __restrict__ out1)
{
  const size_t i = (size_t)blockIdx.x * 256 + threadIdx.x;
  const int b = (int)(i >> 18);        // SS*DD = 262144
  const int d = (int)(i & 63);
  out1[i] = __expf(attn[i]) / z2[b*DD + d];
}

extern "C" void kernel_launch(void* const* d_in, const int* in_sizes, int n_in,
                              void* d_out, int out_size, void* d_ws, size_t ws_size,
                              hipStream_t stream) {
  const float* q = (const float*)d_in[0];
  const float* k = (const float*)d_in[1];
  const float* v = (const float*)d_in[2];
  float* out0 = (float*)d_out;
  float* out1 = out0 + (size_t)BB * SS * DD;

  // bf16 Q/K scratch lives in the out1 region (overwritten by k6w at the end).
  ushort_t* QB = (ushort_t*)out1;                 // 2 MB
  ushort_t* KB = QB + (size_t)BB * SS * DD;       // 2 MB

  float* ws = (float*)d_ws;
  ushort_t* VT = (ushort_t*)ws;                              // 2 MB bf16
  float* Zp = (float*)(VT + (size_t)BB * DD * SS);           // QSPLIT*BB*SS
  float* z2 = Zp + (size_t)QSPLIT * BB * SS;                 // BB*DD

  hipLaunchKernelGGL(p0_convert, dim3(BB*SS*DD/4/256), dim3(256), 0, stream, q, k, QB, KB, out0, z2);
  hipLaunchKernelGGL(pa_colsum, dim3(SS/64, QSPLIT, BB), dim3(256), 0, stream, QB, KB, Zp);
  hipLaunchKernelGGL(p2_vt, dim3(SS/64, BB), dim3(256), 0, stream, v, Zp, VT);
  hipLaunchKernelGGL(pb_attn, dim3(SS/64, KSPLIT, BB), dim3(256), 0, stream, QB, KB, VT, out0);
  hipLaunchKernelGGL(k4f, dim3(BB, SS/64), dim3(256), 0, stream, out0, z2);
  hipLaunchKernelGGL(k6w, dim3(BB*SS*DD/256), dim3(256), 0, stream, out0, z2, out1);
}